// Round 1
// baseline (1811.328 us; speedup 1.0000x reference)
//
#include <hip/hip_runtime.h>
#include <math.h>

#define N_NODES 100000
#define N_EDGES 3200000

// ---------------- CSR build ----------------

__global__ void k_init(int* __restrict__ count) {
    int i = blockIdx.x * blockDim.x + threadIdx.x;
    if (i < N_NODES) count[i] = 0;
}

__global__ void k_hist(const int* __restrict__ dst, int* __restrict__ count) {
    int e = blockIdx.x * blockDim.x + threadIdx.x;   // grid sized exactly E
    atomicAdd(&count[dst[e]], 1);
}

__global__ void k_scan(const int* __restrict__ count, int* __restrict__ row_start,
                       int* __restrict__ cursor, float* __restrict__ dinv) {
    __shared__ int part[1024];
    const int t = threadIdx.x;
    const int chunk = (N_NODES + 1023) / 1024;   // 98
    const int lo = t * chunk;
    const int hi = min(lo + chunk, N_NODES);
    int s = 0;
    for (int i = lo; i < hi; ++i) s += count[i];
    part[t] = s;
    __syncthreads();
    for (int off = 1; off < 1024; off <<= 1) {
        int v = (t >= off) ? part[t - off] : 0;
        __syncthreads();
        part[t] += v;
        __syncthreads();
    }
    int run = (t == 0) ? 0 : part[t - 1];
    for (int i = lo; i < hi; ++i) {
        row_start[i] = run;
        cursor[i] = run;
        int c = count[i];
        run += c;
        dinv[i] = 1.0f / sqrtf((float)(c + 1));   // deg includes self-loop
    }
}

__global__ void k_scatter(const int* __restrict__ src, const int* __restrict__ dst,
                          int* __restrict__ cursor, int* __restrict__ csr_src) {
    int e = blockIdx.x * blockDim.x + threadIdx.x;   // grid sized exactly E
    int d = dst[e];
    int pos = atomicAdd(&cursor[d], 1);
    csr_src[pos] = src[e];
}

// ---------------- MLP 131->64->32->16, fused with first conv transform ----------------
// Writes u0[i] = (h3[i] @ Wc1) * dinv[i]

__global__ __launch_bounds__(256) void k_mlp(
        const float* __restrict__ x,
        const float* __restrict__ W1, const float* __restrict__ b1,
        const float* __restrict__ W2, const float* __restrict__ b2,
        const float* __restrict__ W3, const float* __restrict__ b3,
        const float* __restrict__ Wc1,
        const float* __restrict__ dinv,
        float* __restrict__ u0) {
    __shared__ float sW1[131 * 64];
    __shared__ float sW2[64 * 32];
    __shared__ float sW3[32 * 16];
    __shared__ float sWc[16 * 16];
    __shared__ float sb1[64], sb2[32], sb3[16];
    for (int i = threadIdx.x; i < 131 * 64; i += 256) sW1[i] = W1[i];
    for (int i = threadIdx.x; i < 64 * 32; i += 256) sW2[i] = W2[i];
    for (int i = threadIdx.x; i < 32 * 16; i += 256) sW3[i] = W3[i];
    if (threadIdx.x < 256) sWc[threadIdx.x] = Wc1[threadIdx.x];
    if (threadIdx.x < 64) sb1[threadIdx.x] = b1[threadIdx.x];
    if (threadIdx.x < 32) sb2[threadIdx.x] = b2[threadIdx.x];
    if (threadIdx.x < 16) sb3[threadIdx.x] = b3[threadIdx.x];
    __syncthreads();

    int node = blockIdx.x * 256 + threadIdx.x;
    if (node >= N_NODES) return;

    const float* xr = x + (long)node * 131;

    float a1[64];
#pragma unroll
    for (int j = 0; j < 64; ++j) a1[j] = sb1[j];
    for (int k = 0; k < 131; ++k) {
        float xk = xr[k];
        const float4* wr = reinterpret_cast<const float4*>(sW1 + k * 64);
#pragma unroll
        for (int q = 0; q < 16; ++q) {
            float4 w4 = wr[q];
            a1[4 * q + 0] += xk * w4.x;
            a1[4 * q + 1] += xk * w4.y;
            a1[4 * q + 2] += xk * w4.z;
            a1[4 * q + 3] += xk * w4.w;
        }
    }
#pragma unroll
    for (int j = 0; j < 64; ++j) a1[j] = tanhf(a1[j]);

    float a2[32];
#pragma unroll
    for (int j = 0; j < 32; ++j) a2[j] = sb2[j];
#pragma unroll 4
    for (int k = 0; k < 64; ++k) {
        float hk = a1[k];
        const float4* wr = reinterpret_cast<const float4*>(sW2 + k * 32);
#pragma unroll
        for (int q = 0; q < 8; ++q) {
            float4 w4 = wr[q];
            a2[4 * q + 0] += hk * w4.x;
            a2[4 * q + 1] += hk * w4.y;
            a2[4 * q + 2] += hk * w4.z;
            a2[4 * q + 3] += hk * w4.w;
        }
    }
#pragma unroll
    for (int j = 0; j < 32; ++j) a2[j] = tanhf(a2[j]);

    float a3[16];
#pragma unroll
    for (int j = 0; j < 16; ++j) a3[j] = sb3[j];
#pragma unroll 4
    for (int k = 0; k < 32; ++k) {
        float hk = a2[k];
        const float4* wr = reinterpret_cast<const float4*>(sW3 + k * 16);
#pragma unroll
        for (int q = 0; q < 4; ++q) {
            float4 w4 = wr[q];
            a3[4 * q + 0] += hk * w4.x;
            a3[4 * q + 1] += hk * w4.y;
            a3[4 * q + 2] += hk * w4.z;
            a3[4 * q + 3] += hk * w4.w;
        }
    }
    // no tanh on h3; fuse first conv transform: u0 = (h3 @ Wc1) * dinv
    float dv = dinv[node];
    float uo[16];
#pragma unroll
    for (int j = 0; j < 16; ++j) uo[j] = 0.0f;
#pragma unroll
    for (int k = 0; k < 16; ++k) {
        float hk = a3[k];
        const float4* wr = reinterpret_cast<const float4*>(sWc + k * 16);
#pragma unroll
        for (int q = 0; q < 4; ++q) {
            float4 w4 = wr[q];
            uo[4 * q + 0] += hk * w4.x;
            uo[4 * q + 1] += hk * w4.y;
            uo[4 * q + 2] += hk * w4.z;
            uo[4 * q + 3] += hk * w4.w;
        }
    }
    float4* ur = reinterpret_cast<float4*>(u0 + (long)node * 16);
#pragma unroll
    for (int q = 0; q < 4; ++q) {
        float4 v;
        v.x = uo[4 * q + 0] * dv;
        v.y = uo[4 * q + 1] * dv;
        v.z = uo[4 * q + 2] * dv;
        v.w = uo[4 * q + 3] * dv;
        ur[q] = v;
    }
}

// ---------------- Conv aggregate layer ----------------
// One wave per node: 4 edge-chunk groups x 16 features.
// h_new = tanh(dinv[i] * (sum_{e} u[src_e] + u[i]) + bias)
// mode 0: u_next[i] = (h_new @ Wnext) * dinv[i]
// mode 1: h_out[i] = h_new; cls_out[i] = h_new @ Wcls + bcls

__global__ __launch_bounds__(256) void k_agg(
        const float* __restrict__ u,
        const int* __restrict__ row_start,
        const int* __restrict__ count,
        const int* __restrict__ csr_src,
        const float* __restrict__ dinv,
        const float* __restrict__ bias,
        const float* __restrict__ Wnext,
        float* __restrict__ u_next,
        float* __restrict__ h_out,
        const float* __restrict__ Wcls,
        const float* __restrict__ bcls,
        float* __restrict__ cls_out,
        int mode) {
    const int wave = threadIdx.x >> 6;        // 0..3
    const int lane = threadIdx.x & 63;
    const int grp = lane >> 4;                // 0..3
    const int feat = lane & 15;
    const int node = blockIdx.x * 4 + wave;   // grid*4 == N exactly

    const int rs = row_start[node];
    const int cnt = count[node];
    const float dv = dinv[node];

    float acc = 0.0f;
    for (int e = grp; e < cnt; e += 4) {
        int s = csr_src[rs + e];
        acc += u[(long)s * 16 + feat];
    }
    // reduce the 4 edge-chunk groups -> every lane holds the full edge sum
    acc += __shfl_xor(acc, 16, 64);
    acc += __shfl_xor(acc, 32, 64);
    // self-loop term (u already scaled by dinv[src])
    acc += u[(long)node * 16 + feat];

    float hn = tanhf(dv * acc + bias[feat]);

    if (mode == 0) {
        float t = 0.0f;
        const int base = lane & 48;  // start of this 16-lane group
#pragma unroll
        for (int k = 0; k < 16; ++k) {
            float hk = __shfl(hn, base + k, 64);
            t += hk * Wnext[k * 16 + feat];
        }
        if (grp == 0) u_next[(long)node * 16 + feat] = t * dv;
    } else {
        const int base = lane & 48;
        int f2 = feat & 1;
        float t = 0.0f;
#pragma unroll
        for (int k = 0; k < 16; ++k) {
            float hk = __shfl(hn, base + k, 64);
            t += hk * Wcls[k * 2 + f2];
        }
        if (grp == 0) {
            h_out[(long)node * 16 + feat] = hn;
            if (feat < 2) cls_out[(long)node * 2 + feat] = t + bcls[feat];
        }
    }
}

// ---------------- launch ----------------

extern "C" void kernel_launch(void* const* d_in, const int* in_sizes, int n_in,
                              void* d_out, int out_size, void* d_ws, size_t ws_size,
                              hipStream_t stream) {
    const float* x    = (const float*)d_in[0];
    const int*   ei   = (const int*)d_in[1];
    const float* W1   = (const float*)d_in[2];
    const float* b1   = (const float*)d_in[3];
    const float* W2   = (const float*)d_in[4];
    const float* b2   = (const float*)d_in[5];
    const float* W3   = (const float*)d_in[6];
    const float* b3   = (const float*)d_in[7];
    const float* Wc1  = (const float*)d_in[8];
    const float* bc1  = (const float*)d_in[9];
    const float* Wg   = (const float*)d_in[10];
    const float* bg   = (const float*)d_in[11];
    const float* Wcls = (const float*)d_in[12];
    const float* bcls = (const float*)d_in[13];
    float* out = (float*)d_out;

    const int* src = ei;
    const int* dst = ei + N_EDGES;

    // workspace layout (all 4B elements; u buffers land 64B-aligned)
    int* count     = (int*)d_ws;
    int* cursor    = count + N_NODES;
    int* row_start = cursor + N_NODES;
    float* dinv    = (float*)(row_start + N_NODES);
    int* csr_src   = (int*)(dinv + N_NODES);
    float* u_a     = (float*)(csr_src + N_EDGES);
    float* u_b     = u_a + (long)N_NODES * 16;

    k_init<<<(N_NODES + 255) / 256, 256, 0, stream>>>(count);
    k_hist<<<N_EDGES / 256, 256, 0, stream>>>(dst, count);
    k_scan<<<1, 1024, 0, stream>>>(count, row_start, cursor, dinv);
    k_scatter<<<N_EDGES / 256, 256, 0, stream>>>(src, dst, cursor, csr_src);
    k_mlp<<<(N_NODES + 255) / 256, 256, 0, stream>>>(x, W1, b1, W2, b2, W3, b3,
                                                     Wc1, dinv, u_a);

    float* ua = u_a;
    float* ub = u_b;
    for (int j = 0; j < 10; ++j) {
        const float* bias = (j < 5) ? bc1 : (bg + (long)(j - 5) * 16);
        const float* Wn;
        if (j < 4)      Wn = Wc1;
        else if (j < 9) Wn = Wg + (long)(j - 4) * 256;
        else            Wn = Wcls;  // unused in mode 1
        int mode = (j == 9) ? 1 : 0;
        k_agg<<<N_NODES / 4, 256, 0, stream>>>(ua, row_start, count, csr_src, dinv,
                                               bias, Wn, ub,
                                               out + 200000, Wcls, bcls, out, mode);
        float* tmp = ua; ua = ub; ub = tmp;
    }
}

// Round 2
// 1336.399 us; speedup vs baseline: 1.3554x; 1.3554x over previous
//
#include <hip/hip_runtime.h>
#include <math.h>

#define N_NODES 100000
#define N_EDGES 3200000
#define SCAN_NB ((N_NODES + 255) / 256)   // 391

// ---------------- CSR build ----------------

__global__ void k_init(int* __restrict__ count) {
    int i = blockIdx.x * blockDim.x + threadIdx.x;
    if (i < N_NODES) count[i] = 0;
}

__global__ void k_hist(const int* __restrict__ dst, int* __restrict__ count) {
    int e = blockIdx.x * blockDim.x + threadIdx.x;   // grid sized exactly E
    atomicAdd(&count[dst[e]], 1);
}

// Block-local exclusive scan; row_start[i] = local exclusive prefix, bsum[b] = block total
__global__ __launch_bounds__(256) void k_scan1(const int* __restrict__ count,
                                               int* __restrict__ row_start,
                                               int* __restrict__ bsum) {
    __shared__ int tmp[256];
    const int t = threadIdx.x;
    const int i = blockIdx.x * 256 + t;
    int v = (i < N_NODES) ? count[i] : 0;
    tmp[t] = v;
    __syncthreads();
    for (int off = 1; off < 256; off <<= 1) {
        int a = (t >= off) ? tmp[t - off] : 0;
        __syncthreads();
        tmp[t] += a;
        __syncthreads();
    }
    if (i < N_NODES) row_start[i] = tmp[t] - v;   // exclusive
    if (t == 255) bsum[blockIdx.x] = tmp[255];
}

// Exclusive scan of the 391 block sums (single block, 512 threads)
__global__ __launch_bounds__(512) void k_scan2(int* __restrict__ bsum) {
    __shared__ int tmp[512];
    const int t = threadIdx.x;
    int v = (t < SCAN_NB) ? bsum[t] : 0;
    tmp[t] = v;
    __syncthreads();
    for (int off = 1; off < 512; off <<= 1) {
        int a = (t >= off) ? tmp[t - off] : 0;
        __syncthreads();
        tmp[t] += a;
        __syncthreads();
    }
    if (t < SCAN_NB) bsum[t] = tmp[t] - v;   // exclusive
}

// Add block offsets; produce cursor and dinv
__global__ __launch_bounds__(256) void k_scan3(const int* __restrict__ count,
                                               int* __restrict__ row_start,
                                               const int* __restrict__ bsum,
                                               int* __restrict__ cursor,
                                               float* __restrict__ dinv) {
    const int i = blockIdx.x * 256 + threadIdx.x;
    if (i >= N_NODES) return;
    int rs = row_start[i] + bsum[blockIdx.x];
    row_start[i] = rs;
    cursor[i] = rs;
    dinv[i] = 1.0f / sqrtf((float)(count[i] + 1));   // deg includes self-loop
}

__global__ void k_scatter(const int* __restrict__ src, const int* __restrict__ dst,
                          int* __restrict__ cursor, int* __restrict__ csr_src) {
    int e = blockIdx.x * blockDim.x + threadIdx.x;   // grid sized exactly E
    int d = dst[e];
    int pos = atomicAdd(&cursor[d], 1);
    csr_src[pos] = src[e];
}

// ---------------- MLP 131->64->32->16, fused with first conv transform ----------------
// Weights read via wave-uniform global loads -> s_load + v_fmac (SGPR operand), no LDS.
// Writes u0[i] = (h3[i] @ Wc1) * dinv[i]

__global__ __launch_bounds__(256) void k_mlp(
        const float* __restrict__ x,
        const float* __restrict__ W1, const float* __restrict__ b1,
        const float* __restrict__ W2, const float* __restrict__ b2,
        const float* __restrict__ W3, const float* __restrict__ b3,
        const float* __restrict__ Wc1,
        const float* __restrict__ dinv,
        float* __restrict__ u0) {
    int node = blockIdx.x * 256 + threadIdx.x;
    if (node >= N_NODES) return;

    const float* xr = x + (long)node * 131;

    float a1[64];
#pragma unroll
    for (int j = 0; j < 64; ++j) a1[j] = b1[j];
    for (int k = 0; k < 131; ++k) {
        float xk = xr[k];
        const float* wr = W1 + k * 64;
#pragma unroll
        for (int j = 0; j < 64; ++j) a1[j] += xk * wr[j];
    }
#pragma unroll
    for (int j = 0; j < 64; ++j) a1[j] = tanhf(a1[j]);

    float a2[32];
#pragma unroll
    for (int j = 0; j < 32; ++j) a2[j] = b2[j];
#pragma unroll 2
    for (int k = 0; k < 64; ++k) {
        float hk = a1[k];
        const float* wr = W2 + k * 32;
#pragma unroll
        for (int j = 0; j < 32; ++j) a2[j] += hk * wr[j];
    }
#pragma unroll
    for (int j = 0; j < 32; ++j) a2[j] = tanhf(a2[j]);

    float a3[16];
#pragma unroll
    for (int j = 0; j < 16; ++j) a3[j] = b3[j];
#pragma unroll 4
    for (int k = 0; k < 32; ++k) {
        float hk = a2[k];
        const float* wr = W3 + k * 16;
#pragma unroll
        for (int j = 0; j < 16; ++j) a3[j] += hk * wr[j];
    }
    // no tanh on h3; fuse first conv transform: u0 = (h3 @ Wc1) * dinv
    float dv = dinv[node];
    float uo[16];
#pragma unroll
    for (int j = 0; j < 16; ++j) uo[j] = 0.0f;
#pragma unroll
    for (int k = 0; k < 16; ++k) {
        float hk = a3[k];
        const float* wr = Wc1 + k * 16;
#pragma unroll
        for (int j = 0; j < 16; ++j) uo[j] += hk * wr[j];
    }
    float4* ur = reinterpret_cast<float4*>(u0 + (long)node * 16);
#pragma unroll
    for (int q = 0; q < 4; ++q) {
        float4 v;
        v.x = uo[4 * q + 0] * dv;
        v.y = uo[4 * q + 1] * dv;
        v.z = uo[4 * q + 2] * dv;
        v.w = uo[4 * q + 3] * dv;
        ur[q] = v;
    }
}

// ---------------- Conv aggregate layer ----------------
// One wave per node: 64-wide coalesced index chunk, fully-unrolled gather (all u-row
// loads of a chunk in flight simultaneously), 4 edge-groups x 16 features.
// h_new = tanh(dinv[i] * (sum_e u[src_e] + u[i]) + bias)
// mode 0: u_next[i] = (h_new @ Wnext) * dinv[i]
// mode 1: h_out[i] = h_new; cls_out[i] = h_new @ Wcls + bcls

__global__ __launch_bounds__(256) void k_agg(
        const float* __restrict__ u,
        const int* __restrict__ row_start,
        const int* __restrict__ count,
        const int* __restrict__ csr_src,
        const float* __restrict__ dinv,
        const float* __restrict__ bias,
        const float* __restrict__ Wnext,
        float* __restrict__ u_next,
        float* __restrict__ h_out,
        const float* __restrict__ Wcls,
        const float* __restrict__ bcls,
        float* __restrict__ cls_out,
        int mode) {
    const int wave = threadIdx.x >> 6;        // 0..3
    const int lane = threadIdx.x & 63;
    const int grp = lane >> 4;                // 0..3
    const int feat = lane & 15;
    const int gbase = lane & 48;              // start lane of this 16-lane group
    const int node = blockIdx.x * 4 + wave;   // grid*4 == N exactly

    const int rs = row_start[node];
    const int cnt = count[node];
    const float dv = dinv[node];

    float acc = 0.0f;
    for (int base = 0; base < cnt; base += 64) {
        // one coalesced load covers 64 edge indices (may overread into u buffers: safe)
        int idx = csr_src[rs + base + lane];
#pragma unroll
        for (int k = 0; k < 16; ++k) {
            int e = base + 4 * k + grp;
            int s = __shfl(idx, 4 * k + grp, 64);
            if (e < cnt) acc += u[(long)s * 16 + feat];
        }
    }
    // reduce the 4 edge-groups -> full edge sum in every lane
    acc += __shfl_xor(acc, 16, 64);
    acc += __shfl_xor(acc, 32, 64);
    // self-loop term (u already scaled by dinv[src])
    acc += u[(long)node * 16 + feat];

    float hn = tanhf(dv * acc + bias[feat]);   // replicated across all 4 groups

    // 16x16 transform split across groups: group g handles k in [4g, 4g+4)
    if (mode == 0) {
        float t = 0.0f;
#pragma unroll
        for (int j = 0; j < 4; ++j) {
            int k = 4 * grp + j;
            float hk = __shfl(hn, gbase + k, 64);   // group-local: hn replicated
            t += hk * Wnext[k * 16 + feat];
        }
        t += __shfl_xor(t, 16, 64);
        t += __shfl_xor(t, 32, 64);
        if (grp == 0) u_next[(long)node * 16 + feat] = t * dv;
    } else {
        const int f2 = feat & 1;
        float t = 0.0f;
#pragma unroll
        for (int j = 0; j < 4; ++j) {
            int k = 4 * grp + j;
            float hk = __shfl(hn, gbase + k, 64);
            t += hk * Wcls[k * 2 + f2];
        }
        t += __shfl_xor(t, 16, 64);
        t += __shfl_xor(t, 32, 64);
        if (grp == 0) {
            h_out[(long)node * 16 + feat] = hn;
            if (feat < 2) cls_out[(long)node * 2 + feat] = t + bcls[feat];
        }
    }
}

// ---------------- launch ----------------

extern "C" void kernel_launch(void* const* d_in, const int* in_sizes, int n_in,
                              void* d_out, int out_size, void* d_ws, size_t ws_size,
                              hipStream_t stream) {
    const float* x    = (const float*)d_in[0];
    const int*   ei   = (const int*)d_in[1];
    const float* W1   = (const float*)d_in[2];
    const float* b1   = (const float*)d_in[3];
    const float* W2   = (const float*)d_in[4];
    const float* b2   = (const float*)d_in[5];
    const float* W3   = (const float*)d_in[6];
    const float* b3   = (const float*)d_in[7];
    const float* Wc1  = (const float*)d_in[8];
    const float* bc1  = (const float*)d_in[9];
    const float* Wg   = (const float*)d_in[10];
    const float* bg   = (const float*)d_in[11];
    const float* Wcls = (const float*)d_in[12];
    const float* bcls = (const float*)d_in[13];
    float* out = (float*)d_out;

    const int* src = ei;
    const int* dst = ei + N_EDGES;

    // workspace layout (all 4B elements; u buffers land 64B-aligned)
    int* count     = (int*)d_ws;
    int* cursor    = count + N_NODES;
    int* row_start = cursor + N_NODES;
    float* dinv    = (float*)(row_start + N_NODES);
    int* csr_src   = (int*)(dinv + N_NODES);
    float* u_a     = (float*)(csr_src + N_EDGES);
    float* u_b     = u_a + (long)N_NODES * 16;
    // block sums live in csr_src's first 512 ints: csr_src is only written by
    // k_scatter, which runs after k_scan3 has consumed bsum.
    int* bsum      = csr_src;

    k_init<<<(N_NODES + 255) / 256, 256, 0, stream>>>(count);
    k_hist<<<N_EDGES / 256, 256, 0, stream>>>(dst, count);
    k_scan1<<<SCAN_NB, 256, 0, stream>>>(count, row_start, bsum);
    k_scan2<<<1, 512, 0, stream>>>(bsum);
    k_scan3<<<SCAN_NB, 256, 0, stream>>>(count, row_start, bsum, cursor, dinv);
    k_scatter<<<N_EDGES / 256, 256, 0, stream>>>(src, dst, cursor, csr_src);
    k_mlp<<<(N_NODES + 255) / 256, 256, 0, stream>>>(x, W1, b1, W2, b2, W3, b3,
                                                     Wc1, dinv, u_a);

    float* ua = u_a;
    float* ub = u_b;
    for (int j = 0; j < 10; ++j) {
        const float* bias = (j < 5) ? bc1 : (bg + (long)(j - 5) * 16);
        const float* Wn;
        if (j < 4)      Wn = Wc1;
        else if (j < 9) Wn = Wg + (long)(j - 4) * 256;
        else            Wn = Wcls;  // unused in mode 1
        int mode = (j == 9) ? 1 : 0;
        k_agg<<<N_NODES / 4, 256, 0, stream>>>(ua, row_start, count, csr_src, dinv,
                                               bias, Wn, ub,
                                               out + 200000, Wcls, bcls, out, mode);
        float* tmp = ua; ua = ub; ub = tmp;
    }
}

// Round 3
// 1228.119 us; speedup vs baseline: 1.4749x; 1.0882x over previous
//
#include <hip/hip_runtime.h>
#include <math.h>

#define N_NODES 100000
#define N_EDGES 3200000
#define SCAN_NB ((N_NODES + 255) / 256)   // 391

// Sharded scatter: 8 dst-shards (one per XCD via blockIdx%8 round-robin heuristic)
#define N_SHARDS 8
#define NODES_PER_SHARD (N_NODES / N_SHARDS)   // 12500
#define N_CHUNKS 800
#define EDGES_PER_CHUNK (N_EDGES / N_CHUNKS)   // 4000

// ---------------- CSR build ----------------

__global__ void k_init(int* __restrict__ count) {
    int i = blockIdx.x * blockDim.x + threadIdx.x;
    if (i < N_NODES) count[i] = 0;
}

__global__ void k_hist(const int* __restrict__ dst, int* __restrict__ count) {
    int e = blockIdx.x * blockDim.x + threadIdx.x;   // grid sized exactly E
    atomicAdd(&count[dst[e]], 1);
}

// Block-local exclusive scan; row_start[i] = local exclusive prefix, bsum[b] = block total
__global__ __launch_bounds__(256) void k_scan1(const int* __restrict__ count,
                                               int* __restrict__ row_start,
                                               int* __restrict__ bsum) {
    __shared__ int tmp[256];
    const int t = threadIdx.x;
    const int i = blockIdx.x * 256 + t;
    int v = (i < N_NODES) ? count[i] : 0;
    tmp[t] = v;
    __syncthreads();
    for (int off = 1; off < 256; off <<= 1) {
        int a = (t >= off) ? tmp[t - off] : 0;
        __syncthreads();
        tmp[t] += a;
        __syncthreads();
    }
    if (i < N_NODES) row_start[i] = tmp[t] - v;   // exclusive
    if (t == 255) bsum[blockIdx.x] = tmp[255];
}

// Exclusive scan of the 391 block sums (single block, 512 threads)
__global__ __launch_bounds__(512) void k_scan2(int* __restrict__ bsum) {
    __shared__ int tmp[512];
    const int t = threadIdx.x;
    int v = (t < SCAN_NB) ? bsum[t] : 0;
    tmp[t] = v;
    __syncthreads();
    for (int off = 1; off < 512; off <<= 1) {
        int a = (t >= off) ? tmp[t - off] : 0;
        __syncthreads();
        tmp[t] += a;
        __syncthreads();
    }
    if (t < SCAN_NB) bsum[t] = tmp[t] - v;   // exclusive
}

// Add block offsets; produce cursor and dinv
__global__ __launch_bounds__(256) void k_scan3(const int* __restrict__ count,
                                               int* __restrict__ row_start,
                                               const int* __restrict__ bsum,
                                               int* __restrict__ cursor,
                                               float* __restrict__ dinv) {
    const int i = blockIdx.x * 256 + threadIdx.x;
    if (i >= N_NODES) return;
    int rs = row_start[i] + bsum[blockIdx.x];
    row_start[i] = rs;
    cursor[i] = rs;
    dinv[i] = 1.0f / sqrtf((float)(count[i] + 1));   // deg includes self-loop
}

// Sharded scatter: block b handles edge chunk b/8, but only edges whose dst falls
// in shard b%8's node range. With blockIdx%8 ~ XCD round-robin, each XCD's L2
// caches only its own 1.6 MB csr region -> lines fill completely before writeback
// (194 MB partial-line writeback -> ~13 MB full lines).
__global__ __launch_bounds__(256) void k_scatter(const int* __restrict__ src,
                                                 const int* __restrict__ dst,
                                                 int* __restrict__ cursor,
                                                 int* __restrict__ csr_src) {
    const int shard = blockIdx.x & (N_SHARDS - 1);
    const int chunk = blockIdx.x >> 3;
    const int lo = shard * NODES_PER_SHARD;
    const int hi = lo + NODES_PER_SHARD;
    const int e0 = chunk * EDGES_PER_CHUNK;
    const int e1 = e0 + EDGES_PER_CHUNK;
    for (int e = e0 + threadIdx.x; e < e1; e += 256) {
        int d = dst[e];
        if (d >= lo && d < hi) {
            int pos = atomicAdd(&cursor[d], 1);
            csr_src[pos] = src[e];
        }
    }
}

// ---------------- MLP 131->64->32->16, fused with first conv transform ----------------
// Weights read via wave-uniform global loads -> s_load + v_fmac (SGPR operand), no LDS.
// Writes u0[i] = (h3[i] @ Wc1) * dinv[i]

__global__ __launch_bounds__(256) void k_mlp(
        const float* __restrict__ x,
        const float* __restrict__ W1, const float* __restrict__ b1,
        const float* __restrict__ W2, const float* __restrict__ b2,
        const float* __restrict__ W3, const float* __restrict__ b3,
        const float* __restrict__ Wc1,
        const float* __restrict__ dinv,
        float* __restrict__ u0) {
    int node = blockIdx.x * 256 + threadIdx.x;
    if (node >= N_NODES) return;

    const float* xr = x + (long)node * 131;

    float a1[64];
#pragma unroll
    for (int j = 0; j < 64; ++j) a1[j] = b1[j];
    for (int k = 0; k < 131; ++k) {
        float xk = xr[k];
        const float* wr = W1 + k * 64;
#pragma unroll
        for (int j = 0; j < 64; ++j) a1[j] += xk * wr[j];
    }
#pragma unroll
    for (int j = 0; j < 64; ++j) a1[j] = tanhf(a1[j]);

    float a2[32];
#pragma unroll
    for (int j = 0; j < 32; ++j) a2[j] = b2[j];
#pragma unroll 2
    for (int k = 0; k < 64; ++k) {
        float hk = a1[k];
        const float* wr = W2 + k * 32;
#pragma unroll
        for (int j = 0; j < 32; ++j) a2[j] += hk * wr[j];
    }
#pragma unroll
    for (int j = 0; j < 32; ++j) a2[j] = tanhf(a2[j]);

    float a3[16];
#pragma unroll
    for (int j = 0; j < 16; ++j) a3[j] = b3[j];
#pragma unroll 4
    for (int k = 0; k < 32; ++k) {
        float hk = a2[k];
        const float* wr = W3 + k * 16;
#pragma unroll
        for (int j = 0; j < 16; ++j) a3[j] += hk * wr[j];
    }
    // no tanh on h3; fuse first conv transform: u0 = (h3 @ Wc1) * dinv
    float dv = dinv[node];
    float uo[16];
#pragma unroll
    for (int j = 0; j < 16; ++j) uo[j] = 0.0f;
#pragma unroll
    for (int k = 0; k < 16; ++k) {
        float hk = a3[k];
        const float* wr = Wc1 + k * 16;
#pragma unroll
        for (int j = 0; j < 16; ++j) uo[j] += hk * wr[j];
    }
    float4* ur = reinterpret_cast<float4*>(u0 + (long)node * 16);
#pragma unroll
    for (int q = 0; q < 4; ++q) {
        float4 v;
        v.x = uo[4 * q + 0] * dv;
        v.y = uo[4 * q + 1] * dv;
        v.z = uo[4 * q + 2] * dv;
        v.w = uo[4 * q + 3] * dv;
        ur[q] = v;
    }
}

// ---------------- Conv aggregate layer ----------------
// One wave per node: 64-wide coalesced index chunk, fully-unrolled gather (all u-row
// loads of a chunk in flight simultaneously), 4 edge-groups x 16 features.
// h_new = tanh(dinv[i] * (sum_e u[src_e] + u[i]) + bias)
// mode 0: u_next[i] = (h_new @ Wnext) * dinv[i]
// mode 1: h_out[i] = h_new; cls_out[i] = h_new @ Wcls + bcls

__global__ __launch_bounds__(256) void k_agg(
        const float* __restrict__ u,
        const int* __restrict__ row_start,
        const int* __restrict__ count,
        const int* __restrict__ csr_src,
        const float* __restrict__ dinv,
        const float* __restrict__ bias,
        const float* __restrict__ Wnext,
        float* __restrict__ u_next,
        float* __restrict__ h_out,
        const float* __restrict__ Wcls,
        const float* __restrict__ bcls,
        float* __restrict__ cls_out,
        int mode) {
    const int wave = threadIdx.x >> 6;        // 0..3
    const int lane = threadIdx.x & 63;
    const int grp = lane >> 4;                // 0..3
    const int feat = lane & 15;
    const int gbase = lane & 48;              // start lane of this 16-lane group
    const int node = blockIdx.x * 4 + wave;   // grid*4 == N exactly

    const int rs = row_start[node];
    const int cnt = count[node];
    const float dv = dinv[node];

    float acc = 0.0f;
    for (int base = 0; base < cnt; base += 64) {
        // one coalesced load covers 64 edge indices (may overread into u buffers: safe)
        int idx = csr_src[rs + base + lane];
#pragma unroll
        for (int k = 0; k < 16; ++k) {
            int e = base + 4 * k + grp;
            int s = __shfl(idx, 4 * k + grp, 64);
            if (e < cnt) acc += u[(long)s * 16 + feat];
        }
    }
    // reduce the 4 edge-groups -> full edge sum in every lane
    acc += __shfl_xor(acc, 16, 64);
    acc += __shfl_xor(acc, 32, 64);
    // self-loop term (u already scaled by dinv[src])
    acc += u[(long)node * 16 + feat];

    float hn = tanhf(dv * acc + bias[feat]);   // replicated across all 4 groups

    // 16x16 transform split across groups: group g handles k in [4g, 4g+4)
    if (mode == 0) {
        float t = 0.0f;
#pragma unroll
        for (int j = 0; j < 4; ++j) {
            int k = 4 * grp + j;
            float hk = __shfl(hn, gbase + k, 64);   // group-local: hn replicated
            t += hk * Wnext[k * 16 + feat];
        }
        t += __shfl_xor(t, 16, 64);
        t += __shfl_xor(t, 32, 64);
        if (grp == 0) u_next[(long)node * 16 + feat] = t * dv;
    } else {
        const int f2 = feat & 1;
        float t = 0.0f;
#pragma unroll
        for (int j = 0; j < 4; ++j) {
            int k = 4 * grp + j;
            float hk = __shfl(hn, gbase + k, 64);
            t += hk * Wcls[k * 2 + f2];
        }
        t += __shfl_xor(t, 16, 64);
        t += __shfl_xor(t, 32, 64);
        if (grp == 0) {
            h_out[(long)node * 16 + feat] = hn;
            if (feat < 2) cls_out[(long)node * 2 + feat] = t + bcls[feat];
        }
    }
}

// ---------------- launch ----------------

extern "C" void kernel_launch(void* const* d_in, const int* in_sizes, int n_in,
                              void* d_out, int out_size, void* d_ws, size_t ws_size,
                              hipStream_t stream) {
    const float* x    = (const float*)d_in[0];
    const int*   ei   = (const int*)d_in[1];
    const float* W1   = (const float*)d_in[2];
    const float* b1   = (const float*)d_in[3];
    const float* W2   = (const float*)d_in[4];
    const float* b2   = (const float*)d_in[5];
    const float* W3   = (const float*)d_in[6];
    const float* b3   = (const float*)d_in[7];
    const float* Wc1  = (const float*)d_in[8];
    const float* bc1  = (const float*)d_in[9];
    const float* Wg   = (const float*)d_in[10];
    const float* bg   = (const float*)d_in[11];
    const float* Wcls = (const float*)d_in[12];
    const float* bcls = (const float*)d_in[13];
    float* out = (float*)d_out;

    const int* src = ei;
    const int* dst = ei + N_EDGES;

    // workspace layout (all 4B elements; u buffers land 64B-aligned)
    int* count     = (int*)d_ws;
    int* cursor    = count + N_NODES;
    int* row_start = cursor + N_NODES;
    float* dinv    = (float*)(row_start + N_NODES);
    int* csr_src   = (int*)(dinv + N_NODES);
    float* u_a     = (float*)(csr_src + N_EDGES);
    float* u_b     = u_a + (long)N_NODES * 16;
    // block sums live in csr_src's first 512 ints: csr_src is only written by
    // k_scatter, which runs after k_scan3 has consumed bsum.
    int* bsum      = csr_src;

    k_init<<<(N_NODES + 255) / 256, 256, 0, stream>>>(count);
    k_hist<<<N_EDGES / 256, 256, 0, stream>>>(dst, count);
    k_scan1<<<SCAN_NB, 256, 0, stream>>>(count, row_start, bsum);
    k_scan2<<<1, 512, 0, stream>>>(bsum);
    k_scan3<<<SCAN_NB, 256, 0, stream>>>(count, row_start, bsum, cursor, dinv);
    k_scatter<<<N_CHUNKS * N_SHARDS, 256, 0, stream>>>(src, dst, cursor, csr_src);
    k_mlp<<<(N_NODES + 255) / 256, 256, 0, stream>>>(x, W1, b1, W2, b2, W3, b3,
                                                     Wc1, dinv, u_a);

    float* ua = u_a;
    float* ub = u_b;
    for (int j = 0; j < 10; ++j) {
        const float* bias = (j < 5) ? bc1 : (bg + (long)(j - 5) * 16);
        const float* Wn;
        if (j < 4)      Wn = Wc1;
        else if (j < 9) Wn = Wg + (long)(j - 4) * 256;
        else            Wn = Wcls;  // unused in mode 1
        int mode = (j == 9) ? 1 : 0;
        k_agg<<<N_NODES / 4, 256, 0, stream>>>(ua, row_start, count, csr_src, dinv,
                                               bias, Wn, ub,
                                               out + 200000, Wcls, bcls, out, mode);
        float* tmp = ua; ua = ub; ub = tmp;
    }
}